// Round 11
// baseline (162.106 us; speedup 1.0000x reference)
//
#include <hip/hip_runtime.h>
#include <cstdint>
#include <cstddef>

namespace {

constexpr int NCLS   = 32;
constexpr int KSHOT  = 5;
constexpr int FDIM   = 21168;   // 3*84*84
constexpr int KPAD   = 21248;   // 332 * 64
constexpr int DDIM   = 1600;    // 25 * 64
constexpr int NROW   = 512;     // 32 proto + 480 query
constexpr int NQROW  = 480;
constexpr int NKT    = 332;     // K tiles of 64
constexpr int MAXS   = 15;      // grid = 50*15 = 750 ~ 2.93 blocks/CU (3/CU LDS cap)

using short8 = __attribute__((ext_vector_type(8))) short;
using f32x4  = __attribute__((ext_vector_type(4))) float;

__device__ __forceinline__ unsigned f2bf(float x) {
    union { float f; unsigned u; } v; v.f = x;
    unsigned r = v.u + 0x7fffu + ((v.u >> 16) & 1u);   // RNE
    return r >> 16;
}

// ---------------------------------------------------------------------------
// Kernel 1: build A_bf16 [512][KPAD]; rows 0..31 = 5-shot mean, rest = query.
// ---------------------------------------------------------------------------
__global__ void prep_A(const float* __restrict__ supp,
                       const float* __restrict__ query,
                       unsigned short* __restrict__ A) {
    const int r = blockIdx.y;
    const int u = blockIdx.x * blockDim.x + threadIdx.x;
    if (u >= KPAD / 4) return;
    const int c = u * 4;
    float4 v = make_float4(0.f, 0.f, 0.f, 0.f);
    if (c < FDIM) {   // FDIM % 4 == 0
        if (r < NCLS) {
            const float* s = supp + (size_t)r * KSHOT * FDIM + c;
            float4 a0 = *(const float4*)(s);
            float4 a1 = *(const float4*)(s + FDIM);
            float4 a2 = *(const float4*)(s + 2 * FDIM);
            float4 a3 = *(const float4*)(s + 3 * FDIM);
            float4 a4 = *(const float4*)(s + 4 * FDIM);
            v.x = (a0.x + a1.x + a2.x + a3.x + a4.x) * 0.2f;
            v.y = (a0.y + a1.y + a2.y + a3.y + a4.y) * 0.2f;
            v.z = (a0.z + a1.z + a2.z + a3.z + a4.z) * 0.2f;
            v.w = (a0.w + a1.w + a2.w + a3.w + a4.w) * 0.2f;
        } else {
            v = *(const float4*)(query + (size_t)(r - NCLS) * FDIM + c);
        }
    }
    ushort4 o;
    o.x = (unsigned short)f2bf(v.x); o.y = (unsigned short)f2bf(v.y);
    o.z = (unsigned short)f2bf(v.z); o.w = (unsigned short)f2bf(v.w);
    *(ushort4*)(A + (size_t)r * KPAD + c) = o;
}

// ---------------------------------------------------------------------------
// Kernel 2: fused GEMM (no W prepass). BM=256, BN=64, BK=64, 512 threads =
// 8 waves (4m x 2n), wave tile 64x32, acc[4][2] (32 VGPR).
// A: global_load_lds 16B, XOR-preswizzled source (proven 0-conflict path).
// W: 4 guarded float2 loads/thread/tile, depth-2 reg pipeline (wv holds
// W(t+1) entering tile t; packed to bf16 + XOR-swizzled ds_write_b64 into
// the other Bl buffer; then wv reissued for W(t+2)).
// Slot swizzle includes np>>3 bit -> 2-way (free) bank spread on the pack
// writes; read side uses the matching inverse (k order preserved).
// ---------------------------------------------------------------------------
__global__ __launch_bounds__(512, 4) void gemm9(
        const unsigned short* __restrict__ A,    // [512][KPAD] bf16 bits
        const float* __restrict__ W,             // [FDIM][DDIM] fp32
        float* __restrict__ Cpart, int S) {      // [S][512][DDIM]
    __shared__ unsigned short Al[256 * 64];      // 32 KB (content preswizzled)
    __shared__ unsigned short Bl[2][64 * 64];    // 2 x 8 KB, XOR slot swizzle

    const int bid = blockIdx.x;
    const int s   = bid / 50;
    const int rem = bid % 50;
    const int mt  = rem & 1;         // twins adjacent -> W panel L2-shared
    const int nt  = rem >> 1;        // 0..24
    const int m0  = mt * 256;
    const int n0  = nt * 64;
    const int t0  = (NKT * s) / S;
    const int t1  = (NKT * (s + 1)) / S;

    const int tid  = threadIdx.x;
    const int lane = tid & 63;
    const int w    = tid >> 6;       // 0..7
    const int wr   = w & 3;          // m-wave 0..3
    const int wc   = w >> 2;         // n-wave 0..1
    const int g    = lane >> 4;      // 0..3
    const int r15  = lane & 15;

    // ---- A staging roles (glds, preswizzled source) ----
    const int srow = lane >> 3, sblk = lane & 7;
    const unsigned short* Asrc[4];
    unsigned short* Adst[4];
    #pragma unroll
    for (int i = 0; i < 4; ++i) {
        const int r = w * 32 + i * 8 + srow;     // local row 0..255
        Asrc[i] = A + (size_t)(m0 + r) * KPAD + (size_t)((sblk ^ (r & 7)) * 8);
        Adst[i] = &Al[(w * 32 + i * 8) * 64];
    }

    // ---- W staging roles: n-pair np, k-quad kq ----
    const int np = tid & 31;         // n-pair index (n = 2np, 2np+1)
    const int kq = tid >> 5;         // 0..15
    const float* Wp = W + n0 + 2 * np;
    // slot = kq ^ 2*(np&7) ^ 8*((np>>3)&1): 16 distinct slots per half-wave
    const int bws = (kq ^ (2 * (np & 7)) ^ (8 * ((np >> 3) & 1))) * 4;
    const int wb0 = (2 * np) * 64 + bws;
    const int wb1 = (2 * np + 1) * 64 + bws;

    f32x4 acc[4][2];
    #pragma unroll
    for (int i = 0; i < 4; ++i)
        #pragma unroll
        for (int j = 0; j < 2; ++j)
            acc[i][j] = (f32x4){0.f, 0.f, 0.f, 0.f};

    float2 wv[4];

    // ---- prologue: load W(t0), pack->Bl[0], reissue W(next), glds A(t0) ----
    {
        const int kb = t0 * 64 + kq * 4;
        #pragma unroll
        for (int i = 0; i < 4; ++i)
            wv[i] = (kb + i < FDIM) ? *(const float2*)(Wp + (size_t)(kb + i) * DDIM)
                                    : make_float2(0.f, 0.f);
        uint2 p0, p1;
        p0.x = f2bf(wv[0].x) | (f2bf(wv[1].x) << 16);
        p0.y = f2bf(wv[2].x) | (f2bf(wv[3].x) << 16);
        p1.x = f2bf(wv[0].y) | (f2bf(wv[1].y) << 16);
        p1.y = f2bf(wv[2].y) | (f2bf(wv[3].y) << 16);
        *(uint2*)&Bl[0][wb0] = p0;
        *(uint2*)&Bl[0][wb1] = p1;
    }
    {
        const int tn = (t0 + 1 < t1) ? t0 + 1 : t0;
        const int kb = tn * 64 + kq * 4;
        #pragma unroll
        for (int i = 0; i < 4; ++i)
            wv[i] = (kb + i < FDIM) ? *(const float2*)(Wp + (size_t)(kb + i) * DDIM)
                                    : make_float2(0.f, 0.f);
    }
    #pragma unroll
    for (int i = 0; i < 4; ++i)
        __builtin_amdgcn_global_load_lds(
            (const __attribute__((address_space(1))) void*)(Asrc[i] + t0 * 64),
            (__attribute__((address_space(3))) void*)Adst[i], 16, 0, 0);
    __syncthreads();

    int cur = 0;
    for (int t = t0; t < t1; ++t) {
        const bool m1 = (t + 1 < t1);
        // ---- seg1: pack wv (=W(t+1)) -> Bl[cur^1]; reissue wv = W(t+2) ----
        if (m1) {
            uint2 p0, p1;
            p0.x = f2bf(wv[0].x) | (f2bf(wv[1].x) << 16);
            p0.y = f2bf(wv[2].x) | (f2bf(wv[3].x) << 16);
            p1.x = f2bf(wv[0].y) | (f2bf(wv[1].y) << 16);
            p1.y = f2bf(wv[2].y) | (f2bf(wv[3].y) << 16);
            *(uint2*)&Bl[cur ^ 1][wb0] = p0;
            *(uint2*)&Bl[cur ^ 1][wb1] = p1;
            const int tn = (t + 2 < t1) ? t + 2 : t + 1;
            const int kb = tn * 64 + kq * 4;
            #pragma unroll
            for (int i = 0; i < 4; ++i)
                wv[i] = (kb + i < FDIM) ? *(const float2*)(Wp + (size_t)(kb + i) * DDIM)
                                        : make_float2(0.f, 0.f);
        }
        // ---- compute tile t from Al / Bl[cur] ----
        #pragma unroll
        for (int kk = 0; kk < 2; ++kk) {
            const int q = kk * 4 + g;
            short8 bf[2], af[4];
            #pragma unroll
            for (int ns = 0; ns < 2; ++ns) {
                const int n = wc * 32 + ns * 16 + r15;
                const int rb = q ^ ((n >> 1) & 7) ^ (4 * ((n >> 4) & 1));
                bf[ns] = *(const short8*)&Bl[cur][n * 64 + rb * 8];
            }
            #pragma unroll
            for (int ms = 0; ms < 4; ++ms) {
                const int R = wr * 64 + ms * 16 + r15;
                af[ms] = *(const short8*)&Al[R * 64 + ((q ^ (R & 7)) * 8)];
            }
            #pragma unroll
            for (int ms = 0; ms < 4; ++ms)
                #pragma unroll
                for (int ns = 0; ns < 2; ++ns)
                    acc[ms][ns] = __builtin_amdgcn_mfma_f32_16x16x32_bf16(
                        af[ms], bf[ns], acc[ms][ns], 0, 0, 0);
        }
        __syncthreads();   // b1: all Al/Bl[cur] reads complete
        // ---- seg2: glds A(t+1) (overwrites Al; safe after b1) ----
        if (m1) {
            #pragma unroll
            for (int i = 0; i < 4; ++i)
                __builtin_amdgcn_global_load_lds(
                    (const __attribute__((address_space(1))) void*)(Asrc[i] + (t + 1) * 64),
                    (__attribute__((address_space(3))) void*)Adst[i], 16, 0, 0);
            __syncthreads();   // b2: glds + Bl[cur^1] writes drained
            cur ^= 1;
        }
    }

    // ---- epilogue: write split partial (no guards; exact divisors) ----
    float* Cp = Cpart + (size_t)s * NROW * DDIM;
    #pragma unroll
    for (int ms = 0; ms < 4; ++ms) {
        const int row = m0 + wr * 64 + ms * 16 + g * 4;
        #pragma unroll
        for (int ns = 0; ns < 2; ++ns) {
            const int col = n0 + wc * 32 + ns * 16 + r15;
            #pragma unroll
            for (int r = 0; r < 4; ++r)
                Cp[(size_t)(row + r) * DDIM + col] = acc[ms][ns][r];
        }
    }
}

// ---------------------------------------------------------------------------
// Kernel 3: sum S split partials -> C (float4 vectorized) + per-row inv norm.
// ---------------------------------------------------------------------------
__global__ void reduce_norm(const float* __restrict__ Cpart,
                            float* __restrict__ C,
                            float* __restrict__ inv_norm, int S) {
    const int row = blockIdx.x;
    const int tid = threadIdx.x;
    float acc = 0.f;
    for (int c4 = tid * 4; c4 < DDIM; c4 += 1024) {
        float4 v = make_float4(0.f, 0.f, 0.f, 0.f);
        for (int s2 = 0; s2 < S; ++s2) {
            float4 p = *(const float4*)&Cpart[((size_t)s2 * NROW + row) * DDIM + c4];
            v.x += p.x; v.y += p.y; v.z += p.z; v.w += p.w;
        }
        *(float4*)&C[(size_t)row * DDIM + c4] = v;
        acc += v.x * v.x + v.y * v.y + v.z * v.z + v.w * v.w;
    }
    __shared__ float red[4];
    #pragma unroll
    for (int off = 32; off > 0; off >>= 1) acc += __shfl_xor(acc, off);
    if ((tid & 63) == 0) red[tid >> 6] = acc;
    __syncthreads();
    if (tid == 0) {
        float a = red[0] + red[1] + red[2] + red[3];
        inv_norm[row] = 1.f / fmaxf(sqrtf(a), 1e-8f);
    }
}

// ---------------------------------------------------------------------------
// Kernel 4: fused cosine-sim (480x32) + log_softmax. One block per query row.
// ---------------------------------------------------------------------------
__global__ void simlog(const float* __restrict__ C,
                       const float* __restrict__ inv_norm,
                       float* __restrict__ out) {
    __shared__ float qs[DDIM];
    __shared__ float sims[NCLS];
    const int r = blockIdx.x;
    const int tid = threadIdx.x;
    const float* qrow = C + (size_t)(NCLS + r) * DDIM;
    for (int c = tid; c < DDIM; c += 256) qs[c] = qrow[c];
    __syncthreads();
    const float invq = inv_norm[NCLS + r];
    const int lane = tid & 63, w = tid >> 6;
    #pragma unroll
    for (int j = 0; j < 8; ++j) {
        const int p = w * 8 + j;
        const float* prow = C + (size_t)p * DDIM;
        float d = 0.f;
        for (int c = lane; c < DDIM; c += 64) d += qs[c] * prow[c];
        #pragma unroll
        for (int off = 32; off > 0; off >>= 1) d += __shfl_xor(d, off);
        if (lane == 0) sims[p] = d * invq * inv_norm[p];
    }
    __syncthreads();
    if (w == 0) {
        float v = (lane < NCLS) ? sims[lane] : -1e30f;
        float m = v;
        #pragma unroll
        for (int off = 32; off > 0; off >>= 1) m = fmaxf(m, __shfl_xor(m, off));
        float e = (lane < NCLS) ? expf(v - m) : 0.f;
        float ss = e;
        #pragma unroll
        for (int off = 32; off > 0; off >>= 1) ss += __shfl_xor(ss, off);
        if (lane < NCLS) out[(size_t)r * NCLS + lane] = v - m - logf(ss);
    }
}

} // anonymous namespace

// ws layout (bytes):
//   A_bf16 : 512*21248*2  = 21,757,952
//   Cpart  : S*512*1600*4 = S*3,276,800   (S=15 -> 49,152,000)
//   C      : 3,276,800
//   invn   : 4,096
// S=15 total ~74.2 MB; S auto-shrinks if ws_size is smaller.

extern "C" void kernel_launch(void* const* d_in, const int* in_sizes, int n_in,
                              void* d_out, int out_size, void* d_ws, size_t ws_size,
                              hipStream_t stream) {
    const float* supp  = (const float*)d_in[0];
    const float* query = (const float*)d_in[1];
    const float* Wenc  = (const float*)d_in[2];
    float* out = (float*)d_out;

    const size_t fixedA = 21757952;
    const size_t slot   = (size_t)NROW * DDIM * 4;

    int S = MAXS;
    if (ws_size > fixedA + slot + 4096) {
        size_t avail = (ws_size - fixedA - slot - 4096) / slot;
        if ((size_t)S > avail) S = (int)avail;
    }
    if (S < 1) S = 1;

    char* ws = (char*)d_ws;
    unsigned short* A = (unsigned short*)ws;
    float* Cpart    = (float*)(ws + fixedA);
    float* C        = (float*)(ws + fixedA + (size_t)S * slot);
    float* inv_norm = (float*)(ws + fixedA + (size_t)(S + 1) * slot);

    hipLaunchKernelGGL(prep_A, dim3((KPAD / 4 + 255) / 256, NROW), dim3(256),
                       0, stream, supp, query, A);
    hipLaunchKernelGGL(gemm9, dim3(50 * S), dim3(512), 0, stream,
                       A, Wenc, Cpart, S);
    hipLaunchKernelGGL(reduce_norm, dim3(NROW), dim3(256), 0, stream,
                       Cpart, C, inv_norm, S);
    hipLaunchKernelGGL(simlog, dim3(NQROW), dim3(256), 0, stream,
                       C, inv_norm, out);
}

// Round 12
// 132.198 us; speedup vs baseline: 1.2262x; 1.2262x over previous
//
#include <hip/hip_runtime.h>
#include <cstdint>
#include <cstddef>

namespace {

constexpr int NCLS   = 32;
constexpr int KSHOT  = 5;
constexpr int FDIM   = 21168;   // 3*84*84
constexpr int KPAD   = 21248;   // 332 * 64
constexpr int DDIM   = 1600;    // 25 * 64
constexpr int NROW   = 512;     // 32 proto + 480 query
constexpr int NQROW  = 480;
constexpr int NKT    = 332;     // K tiles of 64
constexpr int MAXS   = 10;      // grid = 50*10 = 500 ~ 1.95 blocks/CU

using short8 = __attribute__((ext_vector_type(8))) short;
using f32x4  = __attribute__((ext_vector_type(4))) float;

__device__ __forceinline__ unsigned f2bf(float x) {
    union { float f; unsigned u; } v; v.f = x;
    unsigned r = v.u + 0x7fffu + ((v.u >> 16) & 1u);   // RNE
    return r >> 16;
}

// ---------------------------------------------------------------------------
// Kernel 1: build A_bf16 [512][KPAD]; rows 0..31 = 5-shot mean, rest = query.
// ---------------------------------------------------------------------------
__global__ void prep_A(const float* __restrict__ supp,
                       const float* __restrict__ query,
                       unsigned short* __restrict__ A) {
    const int r = blockIdx.y;
    const int u = blockIdx.x * blockDim.x + threadIdx.x;
    if (u >= KPAD / 4) return;
    const int c = u * 4;
    float4 v = make_float4(0.f, 0.f, 0.f, 0.f);
    if (c < FDIM) {   // FDIM % 4 == 0
        if (r < NCLS) {
            const float* s = supp + (size_t)r * KSHOT * FDIM + c;
            float4 a0 = *(const float4*)(s);
            float4 a1 = *(const float4*)(s + FDIM);
            float4 a2 = *(const float4*)(s + 2 * FDIM);
            float4 a3 = *(const float4*)(s + 3 * FDIM);
            float4 a4 = *(const float4*)(s + 4 * FDIM);
            v.x = (a0.x + a1.x + a2.x + a3.x + a4.x) * 0.2f;
            v.y = (a0.y + a1.y + a2.y + a3.y + a4.y) * 0.2f;
            v.z = (a0.z + a1.z + a2.z + a3.z + a4.z) * 0.2f;
            v.w = (a0.w + a1.w + a2.w + a3.w + a4.w) * 0.2f;
        } else {
            v = *(const float4*)(query + (size_t)(r - NCLS) * FDIM + c);
        }
    }
    ushort4 o;
    o.x = (unsigned short)f2bf(v.x); o.y = (unsigned short)f2bf(v.y);
    o.z = (unsigned short)f2bf(v.z); o.w = (unsigned short)f2bf(v.w);
    *(ushort4*)(A + (size_t)r * KPAD + c) = o;
}

// ---------------------------------------------------------------------------
// Kernel 2: fused GEMM, 2-phase double-buffered (catalog T3 minimum recipe).
// BM=256, BN=64, BK=64, 512 threads = 8 waves (4m x 2n), wave tile 64x32.
// Per tile: {pack B(t+1) -> Bl[nxt]; reload wv = W(t+2); glds A(t+1) ->
// Al[nxt]; COMPUTE(cur); one __syncthreads()}. The glds drain (vmcnt0 inside
// the barrier) lands AFTER the compute section -> latency overlapped.
// No inline-asm waitcnts, no sched_barrier (plain compiler scheduling).
// ---------------------------------------------------------------------------
__global__ __launch_bounds__(512, 4) void gemm11(
        const unsigned short* __restrict__ A,    // [512][KPAD] bf16 bits
        const float* __restrict__ W,             // [FDIM][DDIM] fp32
        float* __restrict__ Cpart, int S) {      // [S][512][DDIM]
    __shared__ unsigned short Al[2][256 * 64];   // 2 x 32 KB (preswizzled src)
    __shared__ unsigned short Bl[2][64 * 64];    // 2 x 8 KB, XOR slot swizzle

    // bijective XCD-chunk swizzle (m204): contiguous wgid range per XCD
    const int nwg = gridDim.x, orig = blockIdx.x;
    const int xcd = orig & 7, q8 = nwg >> 3, r8 = nwg & 7;
    const int wgid = (xcd < r8 ? xcd * (q8 + 1) : r8 * (q8 + 1) + (xcd - r8) * q8)
                   + (orig >> 3);

    const int s   = wgid / 50;
    const int rem = wgid % 50;
    const int mt  = rem & 1;         // mt twins adjacent -> W panel L2-shared
    const int nt  = rem >> 1;        // 0..24
    const int m0  = mt * 256;
    const int n0  = nt * 64;
    const int t0  = (NKT * s) / S;
    const int t1  = (NKT * (s + 1)) / S;
    const int tmax = t1 - 1;

    const int tid  = threadIdx.x;
    const int lane = tid & 63;
    const int w    = tid >> 6;       // 0..7
    const int wr   = w & 3;          // m-wave 0..3
    const int wc   = w >> 2;         // n-wave 0..1
    const int g    = lane >> 4;      // 0..3
    const int r15  = lane & 15;

    // ---- A staging roles (glds, preswizzled source) ----
    const int srow = lane >> 3, sblk = lane & 7;
    const unsigned short* Asrc[4];
    int AdstOff[4];
    #pragma unroll
    for (int i = 0; i < 4; ++i) {
        const int r = w * 32 + i * 8 + srow;     // local row 0..255
        Asrc[i] = A + (size_t)(m0 + r) * KPAD + (size_t)((sblk ^ (r & 7)) * 8);
        AdstOff[i] = (w * 32 + i * 8) * 64;
    }

    // ---- W staging roles: n-pair np, k-quad kq ----
    const int np = tid & 31;         // n-pair index (cols 2np, 2np+1)
    const int kq = tid >> 5;         // 0..15
    const float* Wp = W + n0 + 2 * np;
    // slot = kq ^ 2*(np&7) ^ 8*(np>>3 & 1): 2-way (free) bank spread
    const int bws = (kq ^ (2 * (np & 7)) ^ (8 * ((np >> 3) & 1))) * 4;
    const int wb0 = (2 * np) * 64 + bws;
    const int wb1 = (2 * np + 1) * 64 + bws;

    f32x4 acc[4][2];
    #pragma unroll
    for (int i = 0; i < 4; ++i)
        #pragma unroll
        for (int j = 0; j < 2; ++j)
            acc[i][j] = (f32x4){0.f, 0.f, 0.f, 0.f};

    float2 wv[4];

#define LOAD_W(t) { const int kb_ = (t) * 64 + kq * 4; _Pragma("unroll") \
    for (int i = 0; i < 4; ++i) \
        wv[i] = (kb_ + i < FDIM) ? *(const float2*)(Wp + (size_t)(kb_ + i) * DDIM) \
                                 : make_float2(0.f, 0.f); }

#define PACK_B(buf) { uint2 p0_, p1_; \
    p0_.x = f2bf(wv[0].x) | (f2bf(wv[1].x) << 16); \
    p0_.y = f2bf(wv[2].x) | (f2bf(wv[3].x) << 16); \
    p1_.x = f2bf(wv[0].y) | (f2bf(wv[1].y) << 16); \
    p1_.y = f2bf(wv[2].y) | (f2bf(wv[3].y) << 16); \
    *(uint2*)&Bl[buf][wb0] = p0_; *(uint2*)&Bl[buf][wb1] = p1_; }

#define GLDS_A(buf, t) { _Pragma("unroll") \
    for (int i = 0; i < 4; ++i) \
        __builtin_amdgcn_global_load_lds( \
            (const __attribute__((address_space(1))) void*)(Asrc[i] + (size_t)(t) * 64), \
            (__attribute__((address_space(3))) void*)(&Al[buf][AdstOff[i]]), 16, 0, 0); }

#define COMPUTE(buf) { _Pragma("unroll") \
    for (int kk = 0; kk < 2; ++kk) { \
        const int q_ = kk * 4 + g; \
        short8 bf_[2], af_[4]; \
        _Pragma("unroll") \
        for (int ns = 0; ns < 2; ++ns) { \
            const int n_ = wc * 32 + ns * 16 + r15; \
            const int rb_ = q_ ^ ((n_ >> 1) & 7) ^ (4 * ((n_ >> 4) & 1)); \
            bf_[ns] = *(const short8*)&Bl[buf][n_ * 64 + rb_ * 8]; \
        } \
        _Pragma("unroll") \
        for (int ms = 0; ms < 4; ++ms) { \
            const int R_ = wr * 64 + ms * 16 + r15; \
            af_[ms] = *(const short8*)&Al[buf][R_ * 64 + ((q_ ^ (R_ & 7)) * 8)]; \
        } \
        _Pragma("unroll") \
        for (int ms = 0; ms < 4; ++ms) \
            _Pragma("unroll") \
            for (int ns = 0; ns < 2; ++ns) \
                acc[ms][ns] = __builtin_amdgcn_mfma_f32_16x16x32_bf16( \
                    af_[ms], bf_[ns], acc[ms][ns], 0, 0, 0); } }

    // ---- prologue: B(t0)->Bl[0], wv=W(t0+1), A(t0)->Al[0] ----
    LOAD_W(t0);
    PACK_B(0);
    LOAD_W(min(t0 + 1, tmax));
    GLDS_A(0, t0);
    __syncthreads();

    // ---- main loop: stage(next) BEFORE compute(cur); 1 barrier/tile ----
    int cur = 0;
    for (int t = t0; t < t1; ++t) {
        const bool m1 = (t + 1 < t1);
        if (m1) {
            PACK_B(cur ^ 1);                 // B(t+1) from wv
            LOAD_W(min(t + 2, tmax));        // wv = W(t+2), full-tile window
            GLDS_A(cur ^ 1, t + 1);          // A(t+1), drains at barrier below
        }
        COMPUTE(cur);
        __syncthreads();                     // single drain point per tile
        if (m1) cur ^= 1;
    }

#undef LOAD_W
#undef PACK_B
#undef GLDS_A
#undef COMPUTE

    // ---- epilogue: write split partial (exact divisors, no guards) ----
    float* Cp = Cpart + (size_t)s * NROW * DDIM;
    #pragma unroll
    for (int ms = 0; ms < 4; ++ms) {
        const int row = m0 + wr * 64 + ms * 16 + g * 4;
        #pragma unroll
        for (int ns = 0; ns < 2; ++ns) {
            const int col = n0 + wc * 32 + ns * 16 + r15;
            #pragma unroll
            for (int r = 0; r < 4; ++r)
                Cp[(size_t)(row + r) * DDIM + col] = acc[ms][ns][r];
        }
    }
}

// ---------------------------------------------------------------------------
// Kernel 3: sum S split partials -> C (float4 vectorized) + per-row inv norm.
// ---------------------------------------------------------------------------
__global__ void reduce_norm(const float* __restrict__ Cpart,
                            float* __restrict__ C,
                            float* __restrict__ inv_norm, int S) {
    const int row = blockIdx.x;
    const int tid = threadIdx.x;
    float acc = 0.f;
    for (int c4 = tid * 4; c4 < DDIM; c4 += 1024) {
        float4 v = make_float4(0.f, 0.f, 0.f, 0.f);
        for (int s2 = 0; s2 < S; ++s2) {
            float4 p = *(const float4*)&Cpart[((size_t)s2 * NROW + row) * DDIM + c4];
            v.x += p.x; v.y += p.y; v.z += p.z; v.w += p.w;
        }
        *(float4*)&C[(size_t)row * DDIM + c4] = v;
        acc += v.x * v.x + v.y * v.y + v.z * v.z + v.w * v.w;
    }
    __shared__ float red[4];
    #pragma unroll
    for (int off = 32; off > 0; off >>= 1) acc += __shfl_xor(acc, off);
    if ((tid & 63) == 0) red[tid >> 6] = acc;
    __syncthreads();
    if (tid == 0) {
        float a = red[0] + red[1] + red[2] + red[3];
        inv_norm[row] = 1.f / fmaxf(sqrtf(a), 1e-8f);
    }
}

// ---------------------------------------------------------------------------
// Kernel 4: fused cosine-sim (480x32) + log_softmax. One block per query row.
// ---------------------------------------------------------------------------
__global__ void simlog(const float* __restrict__ C,
                       const float* __restrict__ inv_norm,
                       float* __restrict__ out) {
    __shared__ float qs[DDIM];
    __shared__ float sims[NCLS];
    const int r = blockIdx.x;
    const int tid = threadIdx.x;
    const float* qrow = C + (size_t)(NCLS + r) * DDIM;
    for (int c = tid; c < DDIM; c += 256) qs[c] = qrow[c];
    __syncthreads();
    const float invq = inv_norm[NCLS + r];
    const int lane = tid & 63, w = tid >> 6;
    #pragma unroll
    for (int j = 0; j < 8; ++j) {
        const int p = w * 8 + j;
        const float* prow = C + (size_t)p * DDIM;
        float d = 0.f;
        for (int c = lane; c < DDIM; c += 64) d += qs[c] * prow[c];
        #pragma unroll
        for (int off = 32; off > 0; off >>= 1) d += __shfl_xor(d, off);
        if (lane == 0) sims[p] = d * invq * inv_norm[p];
    }
    __syncthreads();
    if (w == 0) {
        float v = (lane < NCLS) ? sims[lane] : -1e30f;
        float m = v;
        #pragma unroll
        for (int off = 32; off > 0; off >>= 1) m = fmaxf(m, __shfl_xor(m, off));
        float e = (lane < NCLS) ? expf(v - m) : 0.f;
        float ss = e;
        #pragma unroll
        for (int off = 32; off > 0; off >>= 1) ss += __shfl_xor(ss, off);
        if (lane < NCLS) out[(size_t)r * NCLS + lane] = v - m - logf(ss);
    }
}

} // anonymous namespace

// ws layout (bytes):
//   A_bf16 : 512*21248*2  = 21,757,952
//   Cpart  : S*512*1600*4 = S*3,276,800   (S=10 -> 32,768,000)
//   C      : 3,276,800
//   invn   : 4,096
// S=10 total ~57.8 MB; S auto-shrinks if ws_size is smaller.

extern "C" void kernel_launch(void* const* d_in, const int* in_sizes, int n_in,
                              void* d_out, int out_size, void* d_ws, size_t ws_size,
                              hipStream_t stream) {
    const float* supp  = (const float*)d_in[0];
    const float* query = (const float*)d_in[1];
    const float* Wenc  = (const float*)d_in[2];
    float* out = (float*)d_out;

    const size_t fixedA = 21757952;
    const size_t slot   = (size_t)NROW * DDIM * 4;

    int S = MAXS;
    if (ws_size > fixedA + slot + 4096) {
        size_t avail = (ws_size - fixedA - slot - 4096) / slot;
        if ((size_t)S > avail) S = (int)avail;
    }
    if (S < 1) S = 1;

    char* ws = (char*)d_ws;
    unsigned short* A = (unsigned short*)ws;
    float* Cpart    = (float*)(ws + fixedA);
    float* C        = (float*)(ws + fixedA + (size_t)S * slot);
    float* inv_norm = (float*)(ws + fixedA + (size_t)(S + 1) * slot);

    hipLaunchKernelGGL(prep_A, dim3((KPAD / 4 + 255) / 256, NROW), dim3(256),
                       0, stream, supp, query, A);
    hipLaunchKernelGGL(gemm11, dim3(50 * S), dim3(512), 0, stream,
                       A, Wenc, Cpart, S);
    hipLaunchKernelGGL(reduce_norm, dim3(NROW), dim3(256), 0, stream,
                       Cpart, C, inv_norm, S);
    hipLaunchKernelGGL(simlog, dim3(NQROW), dim3(256), 0, stream,
                       C, inv_norm, out);
}